// Round 14
// baseline (173.780 us; speedup 1.0000x reference)
//
#include <hip/hip_runtime.h>
#include <hip/hip_bf16.h>

typedef float f32x4 __attribute__((ext_vector_type(4)));
typedef short bf16x8 __attribute__((ext_vector_type(8)));
typedef unsigned short us8 __attribute__((ext_vector_type(8)));

__device__ __forceinline__ unsigned short f2bf(float f) {
  union { float f; unsigned u; } v; v.f = f;
  return (unsigned short)((v.u + 0x8000u) >> 16);   // round-half-up bf16
}
__device__ __forceinline__ float bf2f(unsigned short u) {
  union { unsigned u; float f; } v; v.u = ((unsigned)u) << 16;
  return v.f;
}

// ---------------------------------------------------------------------------
// Kernel 1: VmatT[b][n][p] (bf16), n = c*16+u*4+v (256), p = pi*64+pj (4096)
// ---------------------------------------------------------------------------
__global__ __launch_bounds__(256) void prep_vmat(const float* __restrict__ x,
                                                 unsigned short* __restrict__ vmatT) {
  int t = blockIdx.x * 256 + threadIdx.x;
  int pc = t & 511;
  int n  = (t >> 9) & 255;
  int b  = t >> 17;
  int c = n >> 4, u = (n >> 2) & 3, v = n & 3;
  int pi = pc >> 3;
  int pj0 = (pc & 7) << 3;
  int row = 2 * pi + u - 1;
  row = row < 0 ? 0 : (row > 127 ? 127 : row);
  const float* xr = x + ((size_t)(b * 16 + c) * 128 + row) * 128;
  us8 o;
#pragma unroll
  for (int e = 0; e < 8; ++e) {
    int col = 2 * (pj0 + e) + v - 1;
    col = col < 0 ? 0 : (col > 127 ? 127 : col);
    o[e] = f2bf(xr[col]);
  }
  *reinterpret_cast<us8*>(vmatT + (size_t)t * 8) = o;
}

// ---------------------------------------------------------------------------
// Kernel 2: A[b][q][n] (bf16) = sum_p scores[b][q][p] * VmatT[b][n][p]
// DEEP-FIFO GEMM v2. M=4096, N=256, K=4096. BQ=128 (512 thr, 8 waves
// M-split), BK=64, 64 K-tiles. LDS = B ring-4 x 32 KB = 128 KB, 1 block/CU.
// R13 (96 KB/CU in flight at the wait) -> 173 us total. This round: B staged
// 3 TILES AHEAD (same ring-4), vmcnt(16): post-wait FIFO = {B(kt+2),
// A(kt+3), B(kt+3), A(kt+4)} = 16 instr = 128 KB/CU (+33%), and each B tile
// rides 2 barriers instead of 1 (B's L2 latency decoupled from the convoy).
//  - A: reg-staged 4 tiles ahead (r0..r3, period-4 static unroll); CONV
//    extracts BEFORE the set is overwritten.
//  - B ring-4 WAR: buf (kt+3)&3 written at iter kt, last read at iter kt-1,
//    separated by barrier(kt-1). RAW: B(kt+1) drains at wait@kt, read @kt+1.
//  - per iter: CONV; STAGE_B(kt+3)[4]; LOAD_A(kt+4)[4]; 32 MFMA;
//    vmcnt(16); barrier.
//  - B source slot pre-swizzled gs=(c&7)^((c>>3)&7); read same XOR.
//  - uniform 64 iters; tail wrap loads (&63) kept alive by asm.
// ---------------------------------------------------------------------------
__global__ __launch_bounds__(512, 2) void gemm_scores_vmat(
    const float* __restrict__ scores,
    const unsigned short* __restrict__ vmatT,
    unsigned short* __restrict__ Amat) {
  __shared__ unsigned short ldsB[4][16384];   // 4 x (256 rows x 64 bf16)

  int bid = blockIdx.x;                        // 256 blocks = 1/CU
  int batch = bid & 7;                         // = XCD id
  int qb = (bid >> 3) << 7;                    // 32 q-blocks of 128
  const int phase = ((bid >> 3) * 2) & 63;

  const int t = threadIdx.x;
  const int lane = t & 63;
  const int wq = t >> 6;                       // wave id 0..7 = M slice
  const int l15 = lane & 15, l16 = lane >> 4;

  // A: per-lane fragment base (row = qb + wq*16 + l15, k-offset l16*8)
  const float* aLane =
      scores + ((size_t)(batch * 4096 + qb + wq * 16 + l15)) * 4096 + l16 * 8;
  const unsigned short* Vb = vmatT + (size_t)batch * 256 * 4096;

  // B staging: 2048 chunks of 16B; thread t takes c = t + i*512, i=0..3.
  const unsigned short* bSrc[4];
#pragma unroll
  for (int i = 0; i < 4; ++i) {
    int c = t + i * 512;
    int gs = (c & 7) ^ ((c >> 3) & 7);
    bSrc[i] = Vb + (size_t)(c >> 3) * 4096 + gs * 8;
  }
  const int pos0 = (l16 ^ (l15 & 7)) << 3;     // swizzled slot, ks=0 (elems)

  f32x4 acc[16];
#pragma unroll
  for (int ni = 0; ni < 16; ++ni) acc[ni] = (f32x4){0.f, 0.f, 0.f, 0.f};

  f32x4 r0[4], r1[4], r2[4], r3[4];   // 4 named A sets (tile = 4 dwordx4)
  bf16x8 fa0, fa1;

#define SB __builtin_amdgcn_sched_barrier(0)
#define STAGE_B(kt, bufi)                                                     \
  {                                                                           \
    int kp_ = ((kt) + phase) & 63;                                            \
    _Pragma("unroll") for (int i = 0; i < 4; ++i)                             \
        __builtin_amdgcn_global_load_lds(                                     \
            (const __attribute__((address_space(1))) void*)(bSrc[i] + (size_t)kp_ * 64), \
            (__attribute__((address_space(3))) void*)&ldsB[bufi][(t + i * 512) * 8], \
            16, 0, 0);                                                        \
  }
#define LOAD_A(kt, rr)                                                        \
  {                                                                           \
    int kp_ = ((kt) + phase) & 63;                                            \
    const float* ap_ = aLane + (size_t)kp_ * 64;                              \
    rr[0] = *(const f32x4*)(ap_);                                             \
    rr[1] = *(const f32x4*)(ap_ + 4);                                         \
    rr[2] = *(const f32x4*)(ap_ + 32);                                        \
    rr[3] = *(const f32x4*)(ap_ + 36);                                        \
  }
#define CONV(rr)                                                              \
  {                                                                           \
    _Pragma("unroll") for (int e = 0; e < 4; ++e) {                           \
      fa0[e] = (short)f2bf(rr[0][e]); fa0[e + 4] = (short)f2bf(rr[1][e]);     \
      fa1[e] = (short)f2bf(rr[2][e]); fa1[e + 4] = (short)f2bf(rr[3][e]);     \
    }                                                                         \
  }
#define MFMAS(bufi)                                                           \
  {                                                                           \
    _Pragma("unroll") for (int ni = 0; ni < 16; ++ni) {                       \
      bf16x8 bv = *(const bf16x8*)(&ldsB[bufi][0] +                           \
                                   (ni * 16 + l15) * 64 + pos0);              \
      acc[ni] = __builtin_amdgcn_mfma_f32_16x16x32_bf16(fa0, bv, acc[ni],     \
                                                        0, 0, 0);             \
    }                                                                         \
    _Pragma("unroll") for (int ni = 0; ni < 16; ++ni) {                       \
      bf16x8 bv = *(const bf16x8*)(&ldsB[bufi][0] +                           \
                                   (ni * 16 + l15) * 64 + (pos0 ^ 32));      \
      acc[ni] = __builtin_amdgcn_mfma_f32_16x16x32_bf16(fa1, bv, acc[ni],     \
                                                        0, 0, 0);             \
    }                                                                         \
  }
// iter body: consume A set m (= kt%4) and buf m; stage B(kt+3)->buf (m+3)&3
#define BODY(m, kt, rr)                                                       \
  {                                                                           \
    CONV(rr);                   /* extract BEFORE reload */                   \
    SB;                                                                       \
    STAGE_B((kt) + 3, ((m) + 3) & 3);                                         \
    SB;                                                                       \
    LOAD_A((kt) + 4, rr);                                                     \
    SB;                                                                       \
    MFMAS(m);                                                                 \
    SB;                                                                       \
    asm volatile("s_waitcnt vmcnt(16)" ::: "memory");                         \
    SB;                                                                       \
    __builtin_amdgcn_s_barrier();                                             \
    SB;                                                                       \
  }

  // ---- prologue: issue B0,B1,A0,A1,B2,A2,A3 (28 instr); vmcnt(16) drains
  // {B0,B1,A0}; remaining 16 = {A1,B2,A2,A3}. Steady state converges @iter1.
  STAGE_B(0, 0);
  SB;
  STAGE_B(1, 1);
  SB;
  LOAD_A(0, r0);
  SB;
  LOAD_A(1, r1);
  SB;
  STAGE_B(2, 2);
  SB;
  LOAD_A(2, r2);
  SB;
  LOAD_A(3, r3);
  SB;
  asm volatile("s_waitcnt vmcnt(16)" ::: "memory");  // B0,B1,A0 landed
  SB;
  __builtin_amdgcn_s_barrier();
  SB;

  // ---- main loop: 64 uniform iters, period-4 static roles
  for (int kt = 0; kt < 64; kt += 4) {
    BODY(0, kt, r0);
    BODY(1, kt + 1, r1);
    BODY(2, kt + 2, r2);
    BODY(3, kt + 3, r3);
  }

  // keep tail wrap prefetches live so the vmcnt FIFO accounting stays exact
  asm volatile("" ::"v"(r0[0][0]), "v"(r1[0][0]), "v"(r2[0][0]), "v"(r3[0][0]),
               "v"(r0[3][0]), "v"(r1[3][0]), "v"(r2[3][0]), "v"(r3[3][0]));

#undef SB
#undef STAGE_B
#undef LOAD_A
#undef CONV
#undef MFMAS
#undef BODY

  // C-write: wave wq owns q-rows qb+wq*16..+15; row=(l16*4+j), col=l15 per ni
  unsigned short* Ao = Amat + ((size_t)(batch * 4096 + qb + wq * 16)) * 256;
#pragma unroll
  for (int ni = 0; ni < 16; ++ni)
#pragma unroll
    for (int j = 0; j < 4; ++j)
      Ao[(size_t)(l16 * 4 + j) * 256 + ni * 16 + l15] = f2bf(acc[ni][j]);
}

// ---------------------------------------------------------------------------
// Kernel 3: out = x + alpha/4 * gathered conv_transpose contributions
// ---------------------------------------------------------------------------
__global__ __launch_bounds__(256) void epilogue_kernel(
    const float* __restrict__ x, const unsigned short* __restrict__ Amat,
    const float* __restrict__ alpha, float* __restrict__ out) {
  int b = blockIdx.x >> 7;
  int h = blockIdx.x & 127;
  int t = threadIdx.x;
  int w = t & 127;
  int cg = t >> 7;

  int ihi = (h + 1) >> 1, u_hi = (h + 1) & 1;
  int jhi = (w + 1) >> 1, v_hi = (w + 1) & 1;
  bool vi_hi = (ihi <= 63), vi_lo = (ihi >= 1);
  bool vj_hi = (jhi <= 63), vj_lo = (jhi >= 1);

  float al = alpha[0] * 0.25f;
  const unsigned short* Ab = Amat + (size_t)b * 4096 * 256;

#pragma unroll
  for (int cc = 0; cc < 8; ++cc) {
    int c = cg * 8 + cc;
    float s = 0.f;
    if (vi_hi) {
      const unsigned short* Ar = Ab + (size_t)(ihi * 64) * 256 + c * 16 + u_hi * 4;
      if (vj_hi) s += bf2f(Ar[jhi * 256 + v_hi]);
      if (vj_lo) s += bf2f(Ar[(jhi - 1) * 256 + v_hi + 2]);
    }
    if (vi_lo) {
      const unsigned short* Ar = Ab + (size_t)((ihi - 1) * 64) * 256 + c * 16 + (u_hi + 2) * 4;
      if (vj_hi) s += bf2f(Ar[jhi * 256 + v_hi]);
      if (vj_lo) s += bf2f(Ar[(jhi - 1) * 256 + v_hi + 2]);
    }
    size_t xi = (((size_t)b * 16 + c) * 128 + h) * 128 + w;
    out[xi] = x[xi] + al * s;
  }
}

extern "C" void kernel_launch(void* const* d_in, const int* in_sizes, int n_in,
                              void* d_out, int out_size, void* d_ws, size_t ws_size,
                              hipStream_t stream) {
  const float* x      = (const float*)d_in[0];
  const float* scores = (const float*)d_in[1];
  const float* alpha  = (const float*)d_in[2];
  float* out = (float*)d_out;

  unsigned short* vmatT = (unsigned short*)d_ws;
  unsigned short* Amat  = (unsigned short*)((char*)d_ws + (size_t)16 * 1024 * 1024);

  prep_vmat<<<4096, 256, 0, stream>>>(x, vmatT);
  gemm_scores_vmat<<<256, 512, 0, stream>>>(scores, vmatT, Amat);
  epilogue_kernel<<<1024, 256, 0, stream>>>(x, Amat, alpha, out);
}